// Round 1
// baseline (9018.965 us; speedup 1.0000x reference)
//
#include <hip/hip_runtime.h>
#include <cstdint>

#define DIM_IN 128
#define HEADS 8
#define DIM_H 16
#define H1 128   // HEADS*DIM_H
#define DIM_OUT 64
#define NEG 0.2f

// ---------------------------------------------------------------------------
// GEMM: C{0,1} = A[N,K] @ B{0,1}[K,M], row-major. blockIdx.z selects (B,C).
// 64x64 output tile, 256 threads, 4x4 microtile/thread, BK=16, A staged
// transposed in LDS (pad 68 keeps float4 alignment + breaks bank stride).
// ---------------------------------------------------------------------------
__global__ __launch_bounds__(256) void gemm_dual(
    const float* __restrict__ A,
    const float* __restrict__ B0, const float* __restrict__ B1,
    float* __restrict__ C0, float* __restrict__ C1,
    int Nrows, int K, int M) {
  const float* __restrict__ B = blockIdx.z ? B1 : B0;
  float* __restrict__ C = blockIdx.z ? C1 : C0;
  __shared__ float As[16][68];
  __shared__ float Bs[16][64];
  const int row0 = blockIdx.x * 64;
  const int col0 = blockIdx.y * 64;
  const int tid = threadIdx.x;
  const int tx = tid & 15, ty = tid >> 4;
  float acc[4][4] = {};
  for (int k0 = 0; k0 < K; k0 += 16) {
    // stage A tile (64 rows x 16 k), transposed
    {
      int r = tid >> 2;
      int kq = (tid & 3) << 2;
      int grow = row0 + r;
      float4 va = make_float4(0.f, 0.f, 0.f, 0.f);
      if (grow < Nrows) va = *(const float4*)(A + (size_t)grow * K + k0 + kq);
      As[kq + 0][r] = va.x; As[kq + 1][r] = va.y;
      As[kq + 2][r] = va.z; As[kq + 3][r] = va.w;
    }
    // stage B tile (16 k x 64 cols)
    {
      int kb = tid >> 4;
      int cb = (tid & 15) << 2;
      *(float4*)&Bs[kb][cb] = *(const float4*)(B + (size_t)(k0 + kb) * M + col0 + cb);
    }
    __syncthreads();
#pragma unroll
    for (int k = 0; k < 16; ++k) {
      float4 a = *(const float4*)&As[k][ty << 2];
      float4 b = *(const float4*)&Bs[k][tx << 2];
      acc[0][0] += a.x * b.x; acc[0][1] += a.x * b.y; acc[0][2] += a.x * b.z; acc[0][3] += a.x * b.w;
      acc[1][0] += a.y * b.x; acc[1][1] += a.y * b.y; acc[1][2] += a.y * b.z; acc[1][3] += a.y * b.w;
      acc[2][0] += a.z * b.x; acc[2][1] += a.z * b.y; acc[2][2] += a.z * b.z; acc[2][3] += a.z * b.w;
      acc[3][0] += a.w * b.x; acc[3][1] += a.w * b.y; acc[3][2] += a.w * b.z; acc[3][3] += a.w * b.w;
    }
    __syncthreads();
  }
#pragma unroll
  for (int i = 0; i < 4; ++i) {
    int row = row0 + (ty << 2) + i;
    if (row < Nrows) {
      float4 v = make_float4(acc[i][0], acc[i][1], acc[i][2], acc[i][3]);
      *(float4*)(C + (size_t)row * M + col0 + (tx << 2)) = v;
    }
  }
}

// ---------------------------------------------------------------------------
// Layer-1 fused edge pass: one thread per (edge, head). Computes
// ev = exp( att1[h,:] . leaky_relu(xl[src,h,:] + xr[dst,h,:]) )
// and accumulates numer[dst,h,:] += ev*xl[src,h,:], denom[dst,h] += ev.
// No segment-max: it cancels exactly in alpha = ev/denom, and logits are
// small (|logit| < ~10) so exp cannot overflow.
// ---------------------------------------------------------------------------
__global__ __launch_bounds__(256) void edge_l1(
    const int* __restrict__ ei, const float* __restrict__ xl,
    const float* __restrict__ xr, const float* __restrict__ att,
    float* __restrict__ numer, float* __restrict__ denom, int E, int N) {
  int t = blockIdx.x * 256 + threadIdx.x;
  int ET8 = (E + N) << 3;
  if (t >= ET8) return;
  int e = t >> 3, h = t & 7;
  int s, d;
  if (e < E) { s = ei[e]; d = ei[E + e]; } else { s = d = e - E; }
  const float4* pl = (const float4*)(xl + ((size_t)s << 7) + (h << 4));
  const float4* pr = (const float4*)(xr + ((size_t)d << 7) + (h << 4));
  const float4* pa = (const float4*)(att + (h << 4));
  float4 l0 = pl[0], l1 = pl[1], l2 = pl[2], l3 = pl[3];
  float4 r0 = pr[0], r1 = pr[1], r2 = pr[2], r3 = pr[3];
  float4 a0 = pa[0], a1 = pa[1], a2 = pa[2], a3 = pa[3];
  float logit = 0.f;
#define TERM(L, R, A) { float v = (L) + (R); v = v > 0.f ? v : NEG * v; logit += (A) * v; }
  TERM(l0.x, r0.x, a0.x) TERM(l0.y, r0.y, a0.y) TERM(l0.z, r0.z, a0.z) TERM(l0.w, r0.w, a0.w)
  TERM(l1.x, r1.x, a1.x) TERM(l1.y, r1.y, a1.y) TERM(l1.z, r1.z, a1.z) TERM(l1.w, r1.w, a1.w)
  TERM(l2.x, r2.x, a2.x) TERM(l2.y, r2.y, a2.y) TERM(l2.z, r2.z, a2.z) TERM(l2.w, r2.w, a2.w)
  TERM(l3.x, r3.x, a3.x) TERM(l3.y, r3.y, a3.y) TERM(l3.z, r3.z, a3.z) TERM(l3.w, r3.w, a3.w)
#undef TERM
  float ev = __expf(logit);
  float* pn = numer + ((size_t)d << 7) + (h << 4);
  atomicAdd(pn + 0,  ev * l0.x); atomicAdd(pn + 1,  ev * l0.y);
  atomicAdd(pn + 2,  ev * l0.z); atomicAdd(pn + 3,  ev * l0.w);
  atomicAdd(pn + 4,  ev * l1.x); atomicAdd(pn + 5,  ev * l1.y);
  atomicAdd(pn + 6,  ev * l1.z); atomicAdd(pn + 7,  ev * l1.w);
  atomicAdd(pn + 8,  ev * l2.x); atomicAdd(pn + 9,  ev * l2.y);
  atomicAdd(pn + 10, ev * l2.z); atomicAdd(pn + 11, ev * l2.w);
  atomicAdd(pn + 12, ev * l3.x); atomicAdd(pn + 13, ev * l3.y);
  atomicAdd(pn + 14, ev * l3.z); atomicAdd(pn + 15, ev * l3.w);
  atomicAdd(denom + ((size_t)d << 3) + h, ev);
}

// ---------------------------------------------------------------------------
// Layer-1 finish: h = elu(numer/denom + b1)
// ---------------------------------------------------------------------------
__global__ __launch_bounds__(256) void finish_l1(
    const float* __restrict__ numer, const float* __restrict__ denom,
    const float* __restrict__ b1, float* __restrict__ hb, int total) {
  int t = blockIdx.x * 256 + threadIdx.x;
  if (t >= total) return;
  int i = t >> 7, j = t & 127;
  float v = numer[t] / denom[(i << 3) + (j >> 4)] + b1[j];
  hb[t] = v > 0.f ? v : expm1f(v);
}

// ---------------------------------------------------------------------------
// Layer-2 fused edge pass: one thread per edge, 1 head, 64 channels.
// ---------------------------------------------------------------------------
__global__ __launch_bounds__(256) void edge_l2(
    const int* __restrict__ ei, const float* __restrict__ xl,
    const float* __restrict__ xr, const float* __restrict__ att,
    float* __restrict__ numer, float* __restrict__ denom, int E, int N) {
  int e = blockIdx.x * 256 + threadIdx.x;
  int ET = E + N;
  if (e >= ET) return;
  int s, d;
  if (e < E) { s = ei[e]; d = ei[E + e]; } else { s = d = e - E; }
  const float4* pl = (const float4*)(xl + ((size_t)s << 6));
  const float4* pr = (const float4*)(xr + ((size_t)d << 6));
  const float4* pa = (const float4*)att;
  float4 lv[16];
  float logit = 0.f;
#pragma unroll
  for (int q = 0; q < 16; ++q) {
    float4 L = pl[q], R = pr[q], A = pa[q];
    lv[q] = L;
    float v;
    v = L.x + R.x; v = v > 0.f ? v : NEG * v; logit += A.x * v;
    v = L.y + R.y; v = v > 0.f ? v : NEG * v; logit += A.y * v;
    v = L.z + R.z; v = v > 0.f ? v : NEG * v; logit += A.z * v;
    v = L.w + R.w; v = v > 0.f ? v : NEG * v; logit += A.w * v;
  }
  float ev = __expf(logit);
  float* pn = numer + ((size_t)d << 6);
#pragma unroll
  for (int q = 0; q < 16; ++q) {
    atomicAdd(pn + 4 * q + 0, ev * lv[q].x);
    atomicAdd(pn + 4 * q + 1, ev * lv[q].y);
    atomicAdd(pn + 4 * q + 2, ev * lv[q].z);
    atomicAdd(pn + 4 * q + 3, ev * lv[q].w);
  }
  atomicAdd(denom + d, ev);
}

// ---------------------------------------------------------------------------
// Layer-2 finish: out = log_softmax(numer/denom + b2) over 64 channels.
// One 64-lane wave per node; channel = lane.
// ---------------------------------------------------------------------------
__global__ __launch_bounds__(256) void finish_l2(
    const float* __restrict__ numer, const float* __restrict__ denom,
    const float* __restrict__ b2, float* __restrict__ out, int N) {
  int t = blockIdx.x * 256 + threadIdx.x;
  int node = t >> 6;
  if (node >= N) return;
  int c = t & 63;
  float v = numer[t] / denom[node] + b2[c];
  float m = v;
#pragma unroll
  for (int o = 32; o > 0; o >>= 1) m = fmaxf(m, __shfl_xor(m, o, 64));
  float s = __expf(v - m);
#pragma unroll
  for (int o = 32; o > 0; o >>= 1) s += __shfl_xor(s, o, 64);
  out[t] = v - m - __logf(s);
}

extern "C" void kernel_launch(void* const* d_in, const int* in_sizes, int n_in,
                              void* d_out, int out_size, void* d_ws, size_t ws_size,
                              hipStream_t stream) {
  const float* x    = (const float*)d_in[0];
  const int*   ei   = (const int*)d_in[1];
  const float* Wl1  = (const float*)d_in[2];
  const float* Wr1  = (const float*)d_in[3];
  const float* att1 = (const float*)d_in[4];
  const float* b1   = (const float*)d_in[5];
  const float* Wl2  = (const float*)d_in[6];
  const float* Wr2  = (const float*)d_in[7];
  const float* att2 = (const float*)d_in[8];
  const float* b2   = (const float*)d_in[9];
  float* out = (float*)d_out;

  const int N = in_sizes[0] / DIM_IN;   // 50000
  const int E = in_sizes[1] / 2;        // 800000
  const int ET = E + N;                 // edges incl. self-loops

  // Workspace layout (floats). xl2/xr2 overlay xl1/xr1; numer2/denom2 overlay
  // numer1/denom1 (re-zeroed on-stream between layers).
  float* ws = (float*)d_ws;
  const size_t szNH = (size_t)N * H1;   // 6.4M floats
  float* xl1 = ws;                      // [N,128]  later xl2 [N,64]
  float* xr1 = ws + szNH;               // [N,128]  later xr2 [N,64]
  float* num = ws + 2 * szNH;           // [N,128]  later numer2 [N,64]
  float* hb  = ws + 3 * szNH;           // [N,128]
  float* den = ws + 4 * szNH;           // [N,8]    later denom2 [N]

  // ---- layer 1 ----
  hipMemsetAsync(num, 0, szNH * sizeof(float), stream);
  hipMemsetAsync(den, 0, (size_t)N * HEADS * sizeof(float), stream);

  dim3 g1((N + 63) / 64, H1 / 64, 2);
  gemm_dual<<<g1, 256, 0, stream>>>(x, Wl1, Wr1, xl1, xr1, N, DIM_IN, H1);

  long t1 = (long)ET * HEADS;
  edge_l1<<<(int)((t1 + 255) / 256), 256, 0, stream>>>(ei, xl1, xr1, att1, num, den, E, N);

  long tn1 = (long)N * H1;
  finish_l1<<<(int)((tn1 + 255) / 256), 256, 0, stream>>>(num, den, b1, hb, (int)tn1);

  // ---- layer 2 ----
  hipMemsetAsync(num, 0, (size_t)N * DIM_OUT * sizeof(float), stream);
  hipMemsetAsync(den, 0, (size_t)N * sizeof(float), stream);

  dim3 g2((N + 63) / 64, DIM_OUT / 64, 2);
  gemm_dual<<<g2, 256, 0, stream>>>(hb, Wl2, Wr2, xl1, xr1, N, H1, DIM_OUT);

  edge_l2<<<(ET + 255) / 256, 256, 0, stream>>>(ei, xl1, xr1, att2, num, den, E, N);

  long tn2 = (long)N * DIM_OUT;
  finish_l2<<<(int)((tn2 + 255) / 256), 256, 0, stream>>>(num, den, b2, out, N);
}

// Round 2
// 475.860 us; speedup vs baseline: 18.9530x; 18.9530x over previous
//
#include <hip/hip_runtime.h>
#include <cstdint>

#define DIM_IN 128
#define HEADS 8
#define DIM_H 16
#define H1 128   // HEADS*DIM_H
#define DIM_OUT 64
#define NEG 0.2f

// ---------------------------------------------------------------------------
// GEMM: C{0,1} = A[N,K] @ B{0,1}[K,M], row-major. blockIdx.z selects (B,C).
// 64x64 output tile, 256 threads, 4x4 microtile/thread, BK=16.
// ---------------------------------------------------------------------------
__global__ __launch_bounds__(256) void gemm_dual(
    const float* __restrict__ A,
    const float* __restrict__ B0, const float* __restrict__ B1,
    float* __restrict__ C0, float* __restrict__ C1,
    int Nrows, int K, int M) {
  const float* __restrict__ B = blockIdx.z ? B1 : B0;
  float* __restrict__ C = blockIdx.z ? C1 : C0;
  __shared__ float As[16][68];
  __shared__ float Bs[16][64];
  const int row0 = blockIdx.x * 64;
  const int col0 = blockIdx.y * 64;
  const int tid = threadIdx.x;
  const int tx = tid & 15, ty = tid >> 4;
  float acc[4][4] = {};
  for (int k0 = 0; k0 < K; k0 += 16) {
    {
      int r = tid >> 2;
      int kq = (tid & 3) << 2;
      int grow = row0 + r;
      float4 va = make_float4(0.f, 0.f, 0.f, 0.f);
      if (grow < Nrows) va = *(const float4*)(A + (size_t)grow * K + k0 + kq);
      As[kq + 0][r] = va.x; As[kq + 1][r] = va.y;
      As[kq + 2][r] = va.z; As[kq + 3][r] = va.w;
    }
    {
      int kb = tid >> 4;
      int cb = (tid & 15) << 2;
      *(float4*)&Bs[kb][cb] = *(const float4*)(B + (size_t)(k0 + kb) * M + col0 + cb);
    }
    __syncthreads();
#pragma unroll
    for (int k = 0; k < 16; ++k) {
      float4 a = *(const float4*)&As[k][ty << 2];
      float4 b = *(const float4*)&Bs[k][tx << 2];
      acc[0][0] += a.x * b.x; acc[0][1] += a.x * b.y; acc[0][2] += a.x * b.z; acc[0][3] += a.x * b.w;
      acc[1][0] += a.y * b.x; acc[1][1] += a.y * b.y; acc[1][2] += a.y * b.z; acc[1][3] += a.y * b.w;
      acc[2][0] += a.z * b.x; acc[2][1] += a.z * b.y; acc[2][2] += a.z * b.z; acc[2][3] += a.z * b.w;
      acc[3][0] += a.w * b.x; acc[3][1] += a.w * b.y; acc[3][2] += a.w * b.z; acc[3][3] += a.w * b.w;
    }
    __syncthreads();
  }
#pragma unroll
  for (int i = 0; i < 4; ++i) {
    int row = row0 + (ty << 2) + i;
    if (row < Nrows) {
      float4 v = make_float4(acc[i][0], acc[i][1], acc[i][2], acc[i][3]);
      *(float4*)(C + (size_t)row * M + col0 + (tx << 2)) = v;
    }
  }
}

// ---------------------------------------------------------------------------
// CSR build: histogram of dst, exclusive scan, scatter src into buckets.
// Self-loops are NOT stored; they're handled inline in the agg kernels.
// ---------------------------------------------------------------------------
__global__ __launch_bounds__(256) void hist_dst(
    const int* __restrict__ ei, int* __restrict__ deg, int E) {
  int e = blockIdx.x * 256 + threadIdx.x;
  if (e < E) atomicAdd(&deg[ei[E + e]], 1);
}

// Single-block exclusive scan over deg[0..N) -> off[0..N], also copies to cursor.
__global__ __launch_bounds__(1024) void scan_deg(
    const int* __restrict__ deg, int* __restrict__ off,
    int* __restrict__ cursor, int N) {
  __shared__ int wsum[16];
  __shared__ int running;
  if (threadIdx.x == 0) running = 0;
  __syncthreads();
  int lane = threadIdx.x & 63;
  int wid = threadIdx.x >> 6;
  for (int base = 0; base < N; base += 1024) {
    int i = base + threadIdx.x;
    int v = (i < N) ? deg[i] : 0;
    int x = v;
#pragma unroll
    for (int o = 1; o < 64; o <<= 1) {
      int y = __shfl_up(x, o, 64);
      if (lane >= o) x += y;
    }
    if (lane == 63) wsum[wid] = x;
    __syncthreads();
    if (threadIdx.x < 16) {
      int w = wsum[threadIdx.x];
#pragma unroll
      for (int o = 1; o < 16; o <<= 1) {
        int y = __shfl_up(w, o, 64);
        if ((int)threadIdx.x >= o) w += y;
      }
      wsum[threadIdx.x] = w;  // inclusive wave-sums
    }
    __syncthreads();
    int prefix = running + (wid ? wsum[wid - 1] : 0);
    int excl = prefix + x - v;
    if (i < N) { off[i] = excl; cursor[i] = excl; }
    int chunk_total = wsum[15];
    __syncthreads();
    if (threadIdx.x == 0) running += chunk_total;
    __syncthreads();
  }
  if (threadIdx.x == 0) off[N] = running;
}

__global__ __launch_bounds__(256) void scatter_src(
    const int* __restrict__ ei, int* __restrict__ cursor,
    int* __restrict__ srcs, int E) {
  int e = blockIdx.x * 256 + threadIdx.x;
  if (e >= E) return;
  int d = ei[E + e];
  int pos = atomicAdd(&cursor[d], 1);
  srcs[pos] = ei[e];
}

// ---------------------------------------------------------------------------
// Layer-1 aggregation, one 64-lane wave per dst node. Lane l owns channels
// (2l, 2l+1); head = l>>3. Logit reduced over the 8-lane head group.
// Epilogue fuses alpha-normalization + bias + ELU -> hb.
// No segment-max: it cancels in alpha = ev/denom; logits are small.
// ---------------------------------------------------------------------------
__global__ __launch_bounds__(256) void agg_l1(
    const int* __restrict__ srcs, const int* __restrict__ off,
    const float* __restrict__ xl, const float* __restrict__ xr,
    const float* __restrict__ att, const float* __restrict__ b1,
    float* __restrict__ hb, int N) {
  int node = (blockIdx.x * 256 + threadIdx.x) >> 6;
  int lane = threadIdx.x & 63;
  if (node >= N) return;
  float2 xrv = *(const float2*)(xr + ((size_t)node << 7) + (lane << 1));
  float2 av  = *(const float2*)(att + (lane << 1));
  float accx = 0.f, accy = 0.f, dsum = 0.f;
  // self-loop
  {
    float2 xv = *(const float2*)(xl + ((size_t)node << 7) + (lane << 1));
    float v0 = xv.x + xrv.x; v0 = v0 > 0.f ? v0 : NEG * v0;
    float v1 = xv.y + xrv.y; v1 = v1 > 0.f ? v1 : NEG * v1;
    float p = av.x * v0 + av.y * v1;
    p += __shfl_xor(p, 1, 64); p += __shfl_xor(p, 2, 64); p += __shfl_xor(p, 4, 64);
    float ev = __expf(p);
    accx += ev * xv.x; accy += ev * xv.y; dsum += ev;
  }
  int beg = off[node], end = off[node + 1];
  for (int base = beg; base < end; base += 64) {
    int nk = min(64, end - base);
    int sv = (lane < nk) ? srcs[base + lane] : 0;
    for (int j = 0; j < nk; ++j) {
      int s = __shfl(sv, j, 64);
      float2 xv = *(const float2*)(xl + ((size_t)s << 7) + (lane << 1));
      float v0 = xv.x + xrv.x; v0 = v0 > 0.f ? v0 : NEG * v0;
      float v1 = xv.y + xrv.y; v1 = v1 > 0.f ? v1 : NEG * v1;
      float p = av.x * v0 + av.y * v1;
      p += __shfl_xor(p, 1, 64); p += __shfl_xor(p, 2, 64); p += __shfl_xor(p, 4, 64);
      float ev = __expf(p);
      accx += ev * xv.x; accy += ev * xv.y; dsum += ev;
    }
  }
  float inv = 1.0f / dsum;
  float2 bv = *(const float2*)(b1 + (lane << 1));
  float o0 = accx * inv + bv.x;
  float o1 = accy * inv + bv.y;
  o0 = o0 > 0.f ? o0 : expm1f(o0);
  o1 = o1 > 0.f ? o1 : expm1f(o1);
  *(float2*)(hb + ((size_t)node << 7) + (lane << 1)) = make_float2(o0, o1);
}

// ---------------------------------------------------------------------------
// Layer-2 aggregation, one wave per dst node, lane = channel (64 channels,
// 1 head). Epilogue fuses alpha-normalization + bias + log_softmax -> out.
// ---------------------------------------------------------------------------
__global__ __launch_bounds__(256) void agg_l2(
    const int* __restrict__ srcs, const int* __restrict__ off,
    const float* __restrict__ xl, const float* __restrict__ xr,
    const float* __restrict__ att, const float* __restrict__ b2,
    float* __restrict__ out, int N) {
  int node = (blockIdx.x * 256 + threadIdx.x) >> 6;
  int lane = threadIdx.x & 63;
  if (node >= N) return;
  float xrv = xr[((size_t)node << 6) + lane];
  float av  = att[lane];
  float acc = 0.f, dsum = 0.f;
  // self-loop
  {
    float xv = xl[((size_t)node << 6) + lane];
    float v = xv + xrv; v = v > 0.f ? v : NEG * v;
    float p = av * v;
#pragma unroll
    for (int o = 1; o < 64; o <<= 1) p += __shfl_xor(p, o, 64);
    float ev = __expf(p);
    acc += ev * xv; dsum += ev;
  }
  int beg = off[node], end = off[node + 1];
  for (int base = beg; base < end; base += 64) {
    int nk = min(64, end - base);
    int sv = (lane < nk) ? srcs[base + lane] : 0;
    for (int j = 0; j < nk; ++j) {
      int s = __shfl(sv, j, 64);
      float xv = xl[((size_t)s << 6) + lane];
      float v = xv + xrv; v = v > 0.f ? v : NEG * v;
      float p = av * v;
#pragma unroll
      for (int o = 1; o < 64; o <<= 1) p += __shfl_xor(p, o, 64);
      float ev = __expf(p);
      acc += ev * xv; dsum += ev;
    }
  }
  float v = acc / dsum + b2[lane];
  float m = v;
#pragma unroll
  for (int o = 1; o < 64; o <<= 1) m = fmaxf(m, __shfl_xor(m, o, 64));
  float s = __expf(v - m);
#pragma unroll
  for (int o = 1; o < 64; o <<= 1) s += __shfl_xor(s, o, 64);
  out[((size_t)node << 6) + lane] = v - m - __logf(s);
}

extern "C" void kernel_launch(void* const* d_in, const int* in_sizes, int n_in,
                              void* d_out, int out_size, void* d_ws, size_t ws_size,
                              hipStream_t stream) {
  const float* x    = (const float*)d_in[0];
  const int*   ei   = (const int*)d_in[1];
  const float* Wl1  = (const float*)d_in[2];
  const float* Wr1  = (const float*)d_in[3];
  const float* att1 = (const float*)d_in[4];
  const float* b1   = (const float*)d_in[5];
  const float* Wl2  = (const float*)d_in[6];
  const float* Wr2  = (const float*)d_in[7];
  const float* att2 = (const float*)d_in[8];
  const float* b2   = (const float*)d_in[9];
  float* out = (float*)d_out;

  const int N = in_sizes[0] / DIM_IN;   // 50000
  const int E = in_sizes[1] / 2;        // 800000

  // Workspace layout (floats first, then ints). xl2/xr2 overlay xl1/xr1
  // (layer-2 needs only N*64 each; hb is a separate buffer).
  float* ws = (float*)d_ws;
  const size_t szNH = (size_t)N * H1;   // 6.4M floats
  float* xl1 = ws;                      // [N,128] ; layer2: xl2 [N,64]
  float* xr1 = ws + szNH;               // [N,128] ; layer2: xr2 [N,64]
  float* hb  = ws + 2 * szNH;           // [N,128]
  int* ibase  = (int*)(ws + 3 * szNH);
  int* deg    = ibase;                  // [N]
  int* off    = ibase + N;              // [N+1]
  int* cursor = ibase + 2 * N + 1;      // [N]
  int* srcs   = ibase + 3 * N + 1;      // [E]

  // ---- CSR build (shared by both layers) ----
  hipMemsetAsync(deg, 0, (size_t)N * sizeof(int), stream);
  hist_dst<<<(E + 255) / 256, 256, 0, stream>>>(ei, deg, E);
  scan_deg<<<1, 1024, 0, stream>>>(deg, off, cursor, N);
  scatter_src<<<(E + 255) / 256, 256, 0, stream>>>(ei, cursor, srcs, E);

  // ---- layer 1 ----
  dim3 g1((N + 63) / 64, H1 / 64, 2);
  gemm_dual<<<g1, 256, 0, stream>>>(x, Wl1, Wr1, xl1, xr1, N, DIM_IN, H1);
  agg_l1<<<(N + 3) / 4, 256, 0, stream>>>(srcs, off, xl1, xr1, att1, b1, hb, N);

  // ---- layer 2 ----
  dim3 g2((N + 63) / 64, DIM_OUT / 64, 2);
  gemm_dual<<<g2, 256, 0, stream>>>(hb, Wl2, Wr2, xl1, xr1, N, H1, DIM_OUT);
  agg_l2<<<(N + 3) / 4, 256, 0, stream>>>(srcs, off, xl1, xr1, att2, b2, out, N);
}